// Round 1
// baseline (750.808 us; speedup 1.0000x reference)
//
#include <hip/hip_runtime.h>
#include <hip/hip_bf16.h>

// Problem shape (from reference): x [B=4, N=50000, Din=128] fp32,
// W [128, 64] fp32, E=800000 COO edges shared across batch.
// out = relu( scatter_add_rows( pre[:,cols,:] * vals ) ), pre = x @ W.

#define B_BATCH 4
#define DIN 128
#define DOUT 64
#define GB_ROWS 32   // x-rows per GEMM block

// ---------------- GEMM: pre = x @ W  (M x 128) @ (128 x 64) ----------------
__global__ __launch_bounds__(256) void gemm_xw_kernel(
    const float* __restrict__ x, const float* __restrict__ w,
    float* __restrict__ pre, int M) {
  __shared__ float xs[GB_ROWS][DIN + 1];   // +1 pad -> conflict-free column reads
  __shared__ float ws[DIN][DOUT];          // 32 KB

  const int t = threadIdx.x;

  // stage W: 128*64 = 8192 floats = 2048 float4
  for (int i = t; i < 2048; i += 256) {
    ((float4*)ws)[i] = ((const float4*)w)[i];
  }

  // stage x tile: 32 rows * 128 = 4096 floats = 1024 float4 (4 per thread)
  const long base = (long)blockIdx.x * GB_ROWS;
#pragma unroll
  for (int i = 0; i < 4; ++i) {
    int f = (i * 256 + t) * 4;           // flat float index in tile
    int row = f >> 7;                    // /128
    int col = f & 127;
    float4 v = *(const float4*)&x[(base + row) * DIN + col];
    xs[row][col + 0] = v.x;
    xs[row][col + 1] = v.y;
    xs[row][col + 2] = v.z;
    xs[row][col + 3] = v.w;
  }
  __syncthreads();

  // each thread: one row, 8 contiguous output channels
  const int row = t >> 3;          // 0..31
  const int o0  = (t & 7) * 8;     // 0,8,...,56

  float acc[8];
#pragma unroll
  for (int j = 0; j < 8; ++j) acc[j] = 0.0f;

#pragma unroll 8
  for (int k = 0; k < DIN; ++k) {
    float xv = xs[row][k];
    float4 w0 = *(const float4*)&ws[k][o0];
    float4 w1 = *(const float4*)&ws[k][o0 + 4];
    acc[0] = fmaf(xv, w0.x, acc[0]);
    acc[1] = fmaf(xv, w0.y, acc[1]);
    acc[2] = fmaf(xv, w0.z, acc[2]);
    acc[3] = fmaf(xv, w0.w, acc[3]);
    acc[4] = fmaf(xv, w1.x, acc[4]);
    acc[5] = fmaf(xv, w1.y, acc[5]);
    acc[6] = fmaf(xv, w1.z, acc[6]);
    acc[7] = fmaf(xv, w1.w, acc[7]);
  }

  long off = (base + row) * DOUT + o0;
  float4 s0 = make_float4(acc[0], acc[1], acc[2], acc[3]);
  float4 s1 = make_float4(acc[4], acc[5], acc[6], acc[7]);
  *(float4*)&pre[off]     = s0;
  *(float4*)&pre[off + 4] = s1;
}

// ---------------- Edge scatter: out[b,row,:] += pre[b,col,:] * val ----------
__global__ __launch_bounds__(256) void scatter_edges_kernel(
    const float* __restrict__ pre, const float* __restrict__ vals,
    const int* __restrict__ rows, const int* __restrict__ cols,
    float* __restrict__ out, int nE, int nodeStride /* = N*DOUT */) {
  const int wid  = blockIdx.x * (blockDim.x >> 6) + (threadIdx.x >> 6);
  const int lane = threadIdx.x & 63;
  if (wid >= nE) return;

  const int r = rows[wid];
  const int c = cols[wid];
  const float v = vals[wid];

  const int cOff = c * DOUT + lane;
  const int rOff = r * DOUT + lane;
#pragma unroll
  for (int b = 0; b < B_BATCH; ++b) {
    float p = pre[b * nodeStride + cOff];
    atomicAdd(&out[b * nodeStride + rOff], p * v);
  }
}

// ---------------- ReLU in place ----------------
__global__ __launch_bounds__(256) void relu_kernel(float* __restrict__ out, int n4) {
  int i = blockIdx.x * blockDim.x + threadIdx.x;
  const int stride = gridDim.x * blockDim.x;
  for (; i < n4; i += stride) {
    float4 v = ((float4*)out)[i];
    v.x = fmaxf(v.x, 0.0f);
    v.y = fmaxf(v.y, 0.0f);
    v.z = fmaxf(v.z, 0.0f);
    v.w = fmaxf(v.w, 0.0f);
    ((float4*)out)[i] = v;
  }
}

extern "C" void kernel_launch(void* const* d_in, const int* in_sizes, int n_in,
                              void* d_out, int out_size, void* d_ws, size_t ws_size,
                              hipStream_t stream) {
  const float* x     = (const float*)d_in[0];
  const float* w     = (const float*)d_in[1];
  const float* evals = (const float*)d_in[2];
  const int*   erows = (const int*)d_in[3];
  const int*   ecols = (const int*)d_in[4];
  float* out = (float*)d_out;

  const int N  = in_sizes[0] / (B_BATCH * DIN);  // 50000
  const int E  = in_sizes[2];                    // 800000
  const int M  = B_BATCH * N;                    // 200000 rows for the GEMM
  const int nodeStride = N * DOUT;

  float* pre = (float*)d_ws;  // needs M*DOUT*4 = 51.2 MB of scratch

  // 1) pre = x @ W
  {
    int blocks = (M + GB_ROWS - 1) / GB_ROWS;   // 6250
    gemm_xw_kernel<<<blocks, 256, 0, stream>>>(x, w, pre, M);
  }

  // 2) zero the accumulator (d_out is poisoned, and we must be replay-safe)
  hipMemsetAsync(d_out, 0, (size_t)out_size * sizeof(float), stream);

  // 3) scatter-add messages
  {
    int wavesPerBlock = 4;                       // 256 threads
    int blocks = (E + wavesPerBlock - 1) / wavesPerBlock;  // 200000
    scatter_edges_kernel<<<blocks, 256, 0, stream>>>(pre, evals, erows, ecols,
                                                     out, E, nodeStride);
  }

  // 4) ReLU in place
  {
    int n4 = out_size / 4;
    int blocks = 2048;
    relu_kernel<<<blocks, 256, 0, stream>>>(out, n4);
  }
}

// Round 2
// 327.795 us; speedup vs baseline: 2.2905x; 2.2905x over previous
//
#include <hip/hip_runtime.h>
#include <hip/hip_bf16.h>

// x [B=4, N=50000, Din=128] fp32, W [128,64] fp32, E=800000 COO edges (shared
// across batch). out = relu( segsum_rows( pre[:,cols,:] * vals ) ), pre = x@W.
//
// Strategy: GEMM -> build CSR by destination row -> per-row gather with fused
// ReLU. Gather reads pre from L2/L3, writes each output element exactly once.

#define B_BATCH 4
#define DIN 128
#define DOUT 64
#define GB_ROWS 32

// ---------------- GEMM: pre = x @ W ----------------
__global__ __launch_bounds__(256) void gemm_xw_kernel(
    const float* __restrict__ x, const float* __restrict__ w,
    float* __restrict__ pre, int M) {
  __shared__ float xs[GB_ROWS][DIN + 1];
  __shared__ float ws[DIN][DOUT];

  const int t = threadIdx.x;
  for (int i = t; i < 2048; i += 256) ((float4*)ws)[i] = ((const float4*)w)[i];

  const long base = (long)blockIdx.x * GB_ROWS;
#pragma unroll
  for (int i = 0; i < 4; ++i) {
    int f = (i * 256 + t) * 4;
    int row = f >> 7;
    int col = f & 127;
    float4 v = *(const float4*)&x[(base + row) * DIN + col];
    xs[row][col + 0] = v.x;
    xs[row][col + 1] = v.y;
    xs[row][col + 2] = v.z;
    xs[row][col + 3] = v.w;
  }
  __syncthreads();

  const int row = t >> 3;
  const int o0  = (t & 7) * 8;

  float acc[8];
#pragma unroll
  for (int j = 0; j < 8; ++j) acc[j] = 0.0f;

#pragma unroll 8
  for (int k = 0; k < DIN; ++k) {
    float xv = xs[row][k];
    float4 w0 = *(const float4*)&ws[k][o0];
    float4 w1 = *(const float4*)&ws[k][o0 + 4];
    acc[0] = fmaf(xv, w0.x, acc[0]);
    acc[1] = fmaf(xv, w0.y, acc[1]);
    acc[2] = fmaf(xv, w0.z, acc[2]);
    acc[3] = fmaf(xv, w0.w, acc[3]);
    acc[4] = fmaf(xv, w1.x, acc[4]);
    acc[5] = fmaf(xv, w1.y, acc[5]);
    acc[6] = fmaf(xv, w1.z, acc[6]);
    acc[7] = fmaf(xv, w1.w, acc[7]);
  }

  long off = (base + row) * DOUT + o0;
  *(float4*)&pre[off]     = make_float4(acc[0], acc[1], acc[2], acc[3]);
  *(float4*)&pre[off + 4] = make_float4(acc[4], acc[5], acc[6], acc[7]);
}

// ---------------- CSR build ----------------
__global__ __launch_bounds__(256) void hist_kernel(
    const int* __restrict__ rows, int* __restrict__ cnt, int nE) {
  int e = blockIdx.x * blockDim.x + threadIdx.x;
  if (e < nE) atomicAdd(&cnt[rows[e]], 1);
}

// single block, 1024 threads: exclusive scan of cnt[0..n) -> offs, pos
__global__ __launch_bounds__(1024) void scan_kernel(
    const int* __restrict__ cnt, int* __restrict__ offs, int* __restrict__ pos,
    int n, int total) {
  __shared__ int wsum[16];
  __shared__ int carry_s;
  const int t = threadIdx.x;
  const int lane = t & 63, wv = t >> 6;
  if (t == 0) carry_s = 0;
  __syncthreads();
  for (int base = 0; base < n; base += 1024) {
    int i = base + t;
    int v = (i < n) ? cnt[i] : 0;
    int s = v;
#pragma unroll
    for (int d = 1; d < 64; d <<= 1) {
      int u = __shfl_up(s, d, 64);
      if (lane >= d) s += u;
    }
    if (lane == 63) wsum[wv] = s;
    __syncthreads();
    if (wv == 0 && lane < 16) {
      int a = wsum[lane];
#pragma unroll
      for (int d = 1; d < 16; d <<= 1) {
        int u = __shfl_up(a, d, 16);
        if (lane >= d) a += u;
      }
      wsum[lane] = a;
    }
    __syncthreads();
    int waveoff = (wv == 0) ? 0 : wsum[wv - 1];
    int carry = carry_s;
    int excl = carry + waveoff + s - v;
    if (i < n) { offs[i] = excl; pos[i] = excl; }
    __syncthreads();
    if (t == 1023) carry_s = carry + wsum[15];
    __syncthreads();
  }
  if (t == 0) offs[n] = total;
}

__global__ __launch_bounds__(256) void fill_kernel(
    const int* __restrict__ rows, const int* __restrict__ cols,
    const float* __restrict__ vals, int* __restrict__ pos,
    int* __restrict__ csorted, float* __restrict__ vsorted, int nE) {
  int e = blockIdx.x * blockDim.x + threadIdx.x;
  if (e >= nE) return;
  int p = atomicAdd(&pos[rows[e]], 1);
  csorted[p] = cols[e];
  vsorted[p] = vals[e];
}

// ---------------- gather: one wave per destination row, fused ReLU ---------
__global__ __launch_bounds__(256) void gather_rows_kernel(
    const float* __restrict__ pre, const int* __restrict__ offs,
    const int* __restrict__ csorted, const float* __restrict__ vsorted,
    float* __restrict__ out, int N, int NS /* = N*DOUT */) {
  const int wid  = blockIdx.x * 4 + (threadIdx.x >> 6);
  const int lane = threadIdx.x & 63;
  if (wid >= N) return;

  const int start = offs[wid];
  const int end   = offs[wid + 1];

  float a0 = 0.f, a1 = 0.f, a2 = 0.f, a3 = 0.f;

  for (int j0 = start; j0 < end; j0 += 64) {
    const int m = min(64, end - j0);
    int   c = (lane < m) ? csorted[j0 + lane] : 0;
    float v = (lane < m) ? vsorted[j0 + lane] : 0.0f;

    int j = 0;
    for (; j + 1 < m; j += 2) {
      int   c0 = __shfl(c, j, 64),     c1 = __shfl(c, j + 1, 64);
      float v0 = __shfl(v, j, 64),     v1 = __shfl(v, j + 1, 64);
      const float* p0 = pre + (long)c0 * DOUT + lane;
      const float* p1 = pre + (long)c1 * DOUT + lane;
      float x00 = p0[0],      x01 = p0[NS],     x02 = p0[2 * NS], x03 = p0[3 * NS];
      float x10 = p1[0],      x11 = p1[NS],     x12 = p1[2 * NS], x13 = p1[3 * NS];
      a0 = fmaf(v0, x00, a0); a1 = fmaf(v0, x01, a1);
      a2 = fmaf(v0, x02, a2); a3 = fmaf(v0, x03, a3);
      a0 = fmaf(v1, x10, a0); a1 = fmaf(v1, x11, a1);
      a2 = fmaf(v1, x12, a2); a3 = fmaf(v1, x13, a3);
    }
    if (j < m) {
      int   cj = __shfl(c, j, 64);
      float vj = __shfl(v, j, 64);
      const float* p = pre + (long)cj * DOUT + lane;
      a0 = fmaf(vj, p[0], a0);
      a1 = fmaf(vj, p[NS], a1);
      a2 = fmaf(vj, p[2 * NS], a2);
      a3 = fmaf(vj, p[3 * NS], a3);
    }
  }

  const long o = (long)wid * DOUT + lane;
  out[o]          = fmaxf(a0, 0.f);
  out[o + NS]     = fmaxf(a1, 0.f);
  out[o + 2 * NS] = fmaxf(a2, 0.f);
  out[o + 3 * NS] = fmaxf(a3, 0.f);
}

// ---------------- fallback (atomic scatter) ----------------
__global__ __launch_bounds__(256) void scatter_edges_kernel(
    const float* __restrict__ pre, const float* __restrict__ vals,
    const int* __restrict__ rows, const int* __restrict__ cols,
    float* __restrict__ out, int nE, int nodeStride) {
  const int wid  = blockIdx.x * (blockDim.x >> 6) + (threadIdx.x >> 6);
  const int lane = threadIdx.x & 63;
  if (wid >= nE) return;
  const int r = rows[wid];
  const int c = cols[wid];
  const float v = vals[wid];
  const int cOff = c * DOUT + lane;
  const int rOff = r * DOUT + lane;
#pragma unroll
  for (int b = 0; b < B_BATCH; ++b) {
    float p = pre[b * nodeStride + cOff];
    atomicAdd(&out[b * nodeStride + rOff], p * v);
  }
}

__global__ __launch_bounds__(256) void relu_kernel(float* __restrict__ out, int n4) {
  int i = blockIdx.x * blockDim.x + threadIdx.x;
  const int stride = gridDim.x * blockDim.x;
  for (; i < n4; i += stride) {
    float4 v = ((float4*)out)[i];
    v.x = fmaxf(v.x, 0.0f);
    v.y = fmaxf(v.y, 0.0f);
    v.z = fmaxf(v.z, 0.0f);
    v.w = fmaxf(v.w, 0.0f);
    ((float4*)out)[i] = v;
  }
}

extern "C" void kernel_launch(void* const* d_in, const int* in_sizes, int n_in,
                              void* d_out, int out_size, void* d_ws, size_t ws_size,
                              hipStream_t stream) {
  const float* x     = (const float*)d_in[0];
  const float* w     = (const float*)d_in[1];
  const float* evals = (const float*)d_in[2];
  const int*   erows = (const int*)d_in[3];
  const int*   ecols = (const int*)d_in[4];
  float* out = (float*)d_out;

  const int N  = in_sizes[0] / (B_BATCH * DIN);   // 50000
  const int E  = in_sizes[2];                     // 800000
  const int M  = B_BATCH * N;                     // 200000
  const int NS = N * DOUT;

  // workspace layout (bytes), 256B-aligned segments
  size_t off = 0;
  auto alloc = [&](size_t bytes) {
    size_t o = off;
    off += (bytes + 255) & ~(size_t)255;
    return o;
  };
  size_t pre_off  = alloc((size_t)M * DOUT * 4);   // 51.2 MB
  size_t cnt_off  = alloc((size_t)N * 4);
  size_t offs_off = alloc((size_t)(N + 1) * 4);
  size_t pos_off  = alloc((size_t)(N + 1) * 4);
  size_t cs_off   = alloc((size_t)E * 4);
  size_t vs_off   = alloc((size_t)E * 4);
  size_t needed = off;

  char* ws = (char*)d_ws;
  float* pre = (float*)(ws + pre_off);

  // 1) pre = x @ W
  gemm_xw_kernel<<<(M + GB_ROWS - 1) / GB_ROWS, 256, 0, stream>>>(x, w, pre, M);

  if (ws_size >= needed) {
    int*   cnt  = (int*)(ws + cnt_off);
    int*   offs = (int*)(ws + offs_off);
    int*   pos  = (int*)(ws + pos_off);
    int*   cs   = (int*)(ws + cs_off);
    float* vs   = (float*)(ws + vs_off);

    hipMemsetAsync(cnt, 0, (size_t)N * 4, stream);
    hist_kernel<<<(E + 255) / 256, 256, 0, stream>>>(erows, cnt, E);
    scan_kernel<<<1, 1024, 0, stream>>>(cnt, offs, pos, N, E);
    fill_kernel<<<(E + 255) / 256, 256, 0, stream>>>(erows, ecols, evals, pos, cs, vs, E);
    gather_rows_kernel<<<(N + 3) / 4, 256, 0, stream>>>(pre, offs, cs, vs, out, N, NS);
  } else {
    // fallback: atomic scatter (previous verified path)
    hipMemsetAsync(d_out, 0, (size_t)out_size * sizeof(float), stream);
    scatter_edges_kernel<<<(E + 3) / 4, 256, 0, stream>>>(pre, evals, erows, ecols,
                                                          out, E, NS);
    relu_kernel<<<2048, 256, 0, stream>>>(out, out_size / 4);
  }
}

// Round 3
// 232.885 us; speedup vs baseline: 3.2239x; 1.4075x over previous
//
#include <hip/hip_runtime.h>
#include <hip/hip_bf16.h>

// x [B=4, N=50000, Din=128] fp32, W [128,64] fp32, E=800000 COO edges (shared
// across batch). out = relu( segsum_rows( pre[:,cols,:] * vals ) ), pre = x@W.
//
// R3: pre stored bf16 in [node][batch][ch] layout (one edge = contiguous 512B),
// gather processes 2 edges per wave-load (lane halves) + unroll, multi-block
// scan, packed (col,val) edge records.

#define B_BATCH 4
#define DIN 128
#define DOUT 64
#define GB_ROWS 32

static __device__ __forceinline__ unsigned short f2bf(float f) {
  unsigned u = __builtin_bit_cast(unsigned, f);
  unsigned r = (u + 0x7fff + ((u >> 16) & 1)) >> 16;   // RNE
  return (unsigned short)r;
}
static __device__ __forceinline__ float lo16(unsigned u) {
  return __builtin_bit_cast(float, u << 16);
}
static __device__ __forceinline__ float hi16(unsigned u) {
  return __builtin_bit_cast(float, u & 0xffff0000u);
}

// ---------------- GEMM: pre16[n][b][ch] = (x @ W) in bf16 ----------------
__global__ __launch_bounds__(256) void gemm_xw_kernel(
    const float* __restrict__ x, const float* __restrict__ w,
    unsigned short* __restrict__ pre16, int N) {
  __shared__ float xs[GB_ROWS][DIN + 1];
  __shared__ float ws[DIN][DOUT];

  const int t = threadIdx.x;
  for (int i = t; i < 2048; i += 256) ((float4*)ws)[i] = ((const float4*)w)[i];

  const long base = (long)blockIdx.x * GB_ROWS;
#pragma unroll
  for (int i = 0; i < 4; ++i) {
    int f = (i * 256 + t) * 4;
    int row = f >> 7;
    int col = f & 127;
    float4 v = *(const float4*)&x[(base + row) * DIN + col];
    xs[row][col + 0] = v.x;
    xs[row][col + 1] = v.y;
    xs[row][col + 2] = v.z;
    xs[row][col + 3] = v.w;
  }
  __syncthreads();

  const int row = t >> 3;
  const int o0  = (t & 7) * 8;

  float acc[8];
#pragma unroll
  for (int j = 0; j < 8; ++j) acc[j] = 0.0f;

#pragma unroll 8
  for (int k = 0; k < DIN; ++k) {
    float xv = xs[row][k];
    float4 w0 = *(const float4*)&ws[k][o0];
    float4 w1 = *(const float4*)&ws[k][o0 + 4];
    acc[0] = fmaf(xv, w0.x, acc[0]);
    acc[1] = fmaf(xv, w0.y, acc[1]);
    acc[2] = fmaf(xv, w0.z, acc[2]);
    acc[3] = fmaf(xv, w0.w, acc[3]);
    acc[4] = fmaf(xv, w1.x, acc[4]);
    acc[5] = fmaf(xv, w1.y, acc[5]);
    acc[6] = fmaf(xv, w1.z, acc[6]);
    acc[7] = fmaf(xv, w1.w, acc[7]);
  }

  // m = b*N + n  ->  element offset n*256 + b*64 + o0 (bf16 elements)
  long m = base + row;
  int b = (int)(m / N);
  int n = (int)(m - (long)b * N);
  size_t off = (size_t)n * 256 + b * 64 + o0;

  unsigned d0 = f2bf(acc[0]) | ((unsigned)f2bf(acc[1]) << 16);
  unsigned d1 = f2bf(acc[2]) | ((unsigned)f2bf(acc[3]) << 16);
  unsigned d2 = f2bf(acc[4]) | ((unsigned)f2bf(acc[5]) << 16);
  unsigned d3 = f2bf(acc[6]) | ((unsigned)f2bf(acc[7]) << 16);
  *(uint4*)&pre16[off] = make_uint4(d0, d1, d2, d3);
}

// ---------------- CSR build ----------------
__global__ __launch_bounds__(256) void hist_kernel(
    const int* __restrict__ rows, int* __restrict__ cnt, int nE) {
  int e = blockIdx.x * blockDim.x + threadIdx.x;
  if (e < nE) atomicAdd(&cnt[rows[e]], 1);
}

// pass 1: per-1024-block exclusive scan (local), block sums out
__global__ __launch_bounds__(1024) void scan1_kernel(
    const int* __restrict__ cnt, int* __restrict__ offs,
    int* __restrict__ bsum, int n) {
  __shared__ int wsum[16];
  const int t = threadIdx.x, lane = t & 63, wv = t >> 6;
  const int i = blockIdx.x * 1024 + t;
  int v = (i < n) ? cnt[i] : 0;
  int s = v;
#pragma unroll
  for (int d = 1; d < 64; d <<= 1) {
    int u = __shfl_up(s, d, 64);
    if (lane >= d) s += u;
  }
  if (lane == 63) wsum[wv] = s;
  __syncthreads();
  if (t < 16) {
    int a = wsum[t];
#pragma unroll
    for (int d = 1; d < 16; d <<= 1) {
      int u = __shfl_up(a, d, 16);
      if (t >= d) a += u;
    }
    wsum[t] = a;
  }
  __syncthreads();
  int woff = wv ? wsum[wv - 1] : 0;
  if (i < n) offs[i] = woff + s - v;   // local exclusive
  if (t == 0) bsum[blockIdx.x] = wsum[15];
}

// pass 2: single wave scans block sums (nb <= 64)
__global__ __launch_bounds__(64) void scan2_kernel(int* __restrict__ bsum, int nb) {
  const int lane = threadIdx.x;
  int v = (lane < nb) ? bsum[lane] : 0;
  int s = v;
#pragma unroll
  for (int d = 1; d < 64; d <<= 1) {
    int u = __shfl_up(s, d, 64);
    if (lane >= d) s += u;
  }
  if (lane < nb) bsum[lane] = s - v;   // exclusive
}

// pass 3: add block offsets, produce pos cursor copy, set offs[n]=E
__global__ __launch_bounds__(256) void scan3_kernel(
    int* __restrict__ offs, const int* __restrict__ bsum,
    int* __restrict__ pos, int n, int total) {
  const int i = blockIdx.x * blockDim.x + threadIdx.x;
  if (i < n) {
    int o = offs[i] + bsum[i >> 10];
    offs[i] = o;
    pos[i] = o;
  }
  if (i == 0) offs[n] = total;
}

// fill packed (col, val_bits) records sorted by destination row
__global__ __launch_bounds__(256) void fill_kernel(
    const int* __restrict__ rows, const int* __restrict__ cols,
    const float* __restrict__ vals, int* __restrict__ pos,
    int2* __restrict__ epk, int nE) {
  int e = blockIdx.x * blockDim.x + threadIdx.x;
  if (e >= nE) return;
  int p = atomicAdd(&pos[rows[e]], 1);
  epk[p] = make_int2(cols[e], __builtin_bit_cast(int, vals[e]));
}

// ---------------- gather: one wave per destination row, fused ReLU ---------
// pre16 layout: [node][batch=4][ch=64] bf16 (512 B per node).
// Lane l (l<32): batch=(l>>3), ch8=(l&7)*8; lanes 32..63 mirror for edge j+1.
__global__ __launch_bounds__(256) void gather_rows_kernel(
    const unsigned short* __restrict__ pre16, const int* __restrict__ offs,
    const int2* __restrict__ epk, float* __restrict__ out, int N, int NS) {
  const int wid  = blockIdx.x * 4 + (threadIdx.x >> 6);
  const int lane = threadIdx.x & 63;
  if (wid >= N) return;

  const int start = offs[wid];
  const int end   = offs[wid + 1];
  const int eh    = lane >> 5;                  // which edge of the pair
  const int loff  = ((lane >> 3) & 3) * 64 + (lane & 7) * 8;  // bf16 elements

  float a0 = 0.f, a1 = 0.f, a2 = 0.f, a3 = 0.f;
  float a4 = 0.f, a5 = 0.f, a6 = 0.f, a7 = 0.f;

  for (int j0 = start; j0 < end; j0 += 64) {
    const int m = min(64, end - j0);
    int   c = 0;
    float v = 0.0f;
    if (lane < m) {
      int2 r = epk[j0 + lane];
      c = r.x;
      v = __builtin_bit_cast(float, r.y);
    }

    auto edge2 = [&](int j) {
      int   cj = __shfl(c, j + eh, 64);
      float vj = __shfl(v, j + eh, 64);
      const uint4 q = *(const uint4*)(pre16 + (size_t)cj * 256 + loff);
      a0 = fmaf(vj, lo16(q.x), a0);
      a1 = fmaf(vj, hi16(q.x), a1);
      a2 = fmaf(vj, lo16(q.y), a2);
      a3 = fmaf(vj, hi16(q.y), a3);
      a4 = fmaf(vj, lo16(q.z), a4);
      a5 = fmaf(vj, hi16(q.z), a5);
      a6 = fmaf(vj, lo16(q.w), a6);
      a7 = fmaf(vj, hi16(q.w), a7);
    };

    int j = 0;
    for (; j + 3 < m; j += 4) { edge2(j); edge2(j + 2); }
    for (; j + 1 < m; j += 2) { edge2(j); }
    if (j < m) {   // odd tail: both half-waves read edge j, upper half adds 0
      int   cj = __shfl(c, j, 64);
      float vj = __shfl(v, j, 64);
      if (eh) vj = 0.0f;
      const uint4 q = *(const uint4*)(pre16 + (size_t)cj * 256 + loff);
      a0 = fmaf(vj, lo16(q.x), a0);
      a1 = fmaf(vj, hi16(q.x), a1);
      a2 = fmaf(vj, lo16(q.y), a2);
      a3 = fmaf(vj, hi16(q.y), a3);
      a4 = fmaf(vj, lo16(q.z), a4);
      a5 = fmaf(vj, hi16(q.z), a5);
      a6 = fmaf(vj, lo16(q.w), a6);
      a7 = fmaf(vj, hi16(q.w), a7);
    }
  }

  // combine the two half-wave edge streams
  a0 += __shfl_xor(a0, 32, 64);
  a1 += __shfl_xor(a1, 32, 64);
  a2 += __shfl_xor(a2, 32, 64);
  a3 += __shfl_xor(a3, 32, 64);
  a4 += __shfl_xor(a4, 32, 64);
  a5 += __shfl_xor(a5, 32, 64);
  a6 += __shfl_xor(a6, 32, 64);
  a7 += __shfl_xor(a7, 32, 64);

  if (lane < 32) {
    const int b   = lane >> 3;
    const int ch8 = (lane & 7) * 8;
    size_t o = (size_t)b * NS + (size_t)wid * DOUT + ch8;
    *(float4*)&out[o]     = make_float4(fmaxf(a0, 0.f), fmaxf(a1, 0.f),
                                        fmaxf(a2, 0.f), fmaxf(a3, 0.f));
    *(float4*)&out[o + 4] = make_float4(fmaxf(a4, 0.f), fmaxf(a5, 0.f),
                                        fmaxf(a6, 0.f), fmaxf(a7, 0.f));
  }
}

extern "C" void kernel_launch(void* const* d_in, const int* in_sizes, int n_in,
                              void* d_out, int out_size, void* d_ws, size_t ws_size,
                              hipStream_t stream) {
  const float* x     = (const float*)d_in[0];
  const float* w     = (const float*)d_in[1];
  const float* evals = (const float*)d_in[2];
  const int*   erows = (const int*)d_in[3];
  const int*   ecols = (const int*)d_in[4];
  float* out = (float*)d_out;

  const int N  = in_sizes[0] / (B_BATCH * DIN);   // 50000
  const int E  = in_sizes[2];                     // 800000
  const int M  = B_BATCH * N;                     // 200000
  const int NS = N * DOUT;
  const int NB = (N + 1023) / 1024;               // scan blocks (<= 64)

  // workspace layout
  size_t off = 0;
  auto alloc = [&](size_t bytes) {
    size_t o = off;
    off += (bytes + 255) & ~(size_t)255;
    return o;
  };
  size_t pre_off  = alloc((size_t)M * DOUT * 2);      // bf16 pre, 25.6 MB
  size_t cnt_off  = alloc((size_t)N * 4);
  size_t offs_off = alloc((size_t)(N + 1) * 4);
  size_t pos_off  = alloc((size_t)(N + 1) * 4);
  size_t epk_off  = alloc((size_t)E * 8);             // packed (col,val)
  size_t bsum_off = alloc((size_t)64 * 4);
  (void)ws_size;

  char* ws = (char*)d_ws;
  unsigned short* pre16 = (unsigned short*)(ws + pre_off);
  int*   cnt  = (int*)(ws + cnt_off);
  int*   offs = (int*)(ws + offs_off);
  int*   pos  = (int*)(ws + pos_off);
  int2*  epk  = (int2*)(ws + epk_off);
  int*   bsum = (int*)(ws + bsum_off);

  // 1) pre = x @ W  (bf16, node-major layout)
  gemm_xw_kernel<<<M / GB_ROWS, 256, 0, stream>>>(x, w, pre16, N);

  // 2) CSR by destination row
  hipMemsetAsync(cnt, 0, (size_t)N * 4, stream);
  hist_kernel<<<(E + 255) / 256, 256, 0, stream>>>(erows, cnt, E);
  scan1_kernel<<<NB, 1024, 0, stream>>>(cnt, offs, bsum, N);
  scan2_kernel<<<1, 64, 0, stream>>>(bsum, NB);
  scan3_kernel<<<(N + 255) / 256, 256, 0, stream>>>(offs, bsum, pos, N, E);
  fill_kernel<<<(E + 255) / 256, 256, 0, stream>>>(erows, ecols, evals, pos, epk, E);

  // 3) gather + fused ReLU
  gather_rows_kernel<<<(N + 3) / 4, 256, 0, stream>>>(pre16, offs, epk, out, N, NS);
}

// Round 4
// 191.153 us; speedup vs baseline: 3.9278x; 1.2183x over previous
//
#include <hip/hip_runtime.h>
#include <hip/hip_bf16.h>

// x [B=4, N=50000, Din=128] fp32, W [128,64] fp32, E=800000 COO edges (shared
// across batch). out = relu( segsum_rows( pre[:,cols,:] * vals ) ), pre = x@W.
//
// R4: GEMM via mfma_f32_16x16x32_bf16 with hi/lo bf16 split (3 terms) for
// fp32-grade accuracy. W fragments precomputed to ws, staged in LDS. x read
// directly from global as A-fragments. Rest identical to R3.

#define B_BATCH 4
#define DIN 128
#define DOUT 64

typedef float f32x4 __attribute__((ext_vector_type(4)));
typedef short s16x8 __attribute__((ext_vector_type(8)));

static __device__ __forceinline__ unsigned short f2bf(float f) {
  unsigned u = __builtin_bit_cast(unsigned, f);
  unsigned r = (u + 0x7fff + ((u >> 16) & 1)) >> 16;   // RNE
  return (unsigned short)r;
}
static __device__ __forceinline__ float lo16(unsigned u) {
  return __builtin_bit_cast(float, u << 16);
}
static __device__ __forceinline__ float hi16(unsigned u) {
  return __builtin_bit_cast(float, u & 0xffff0000u);
}

// ---------------- prep: build W fragment image (hi/lo bf16) ----------------
// Layout: fslot = (ct*4 + ks)*2 + term; entry [fslot][lane] = 16B (short8).
// Frag elem j (j=0..7): k = ks*32 + 16*(j>>2) + 4*((lane>>4)&3) + (j&3),
//                       n = ct*16 + (lane&15).
__global__ __launch_bounds__(256) void prep_wfrag_kernel(
    const float* __restrict__ w, uint4* __restrict__ wimg) {
  const int t = threadIdx.x;
  for (int i = 0; i < 8; ++i) {
    int idx = i * 256 + t;           // 0..2047
    int fslot = idx >> 6;
    int lane = idx & 63;
    int term = fslot & 1;
    int cks = fslot >> 1;
    int ct = cks >> 2, ks = cks & 3;
    int n = ct * 16 + (lane & 15);
    int kb = ks * 32 + 4 * ((lane >> 4) & 3);
    unsigned short e[8];
#pragma unroll
    for (int j = 0; j < 8; ++j) {
      int k = kb + 16 * (j >> 2) + (j & 3);
      float wv = w[k * DOUT + n];
      unsigned ub = __builtin_bit_cast(unsigned, wv);
      unsigned hib = ub & 0xffff0000u;
      if (term == 0) {
        e[j] = (unsigned short)(hib >> 16);
      } else {
        float lof = wv - __builtin_bit_cast(float, hib);
        e[j] = (unsigned short)(__builtin_bit_cast(unsigned, lof) >> 16);
      }
    }
    uint4 q;
    q.x = (unsigned)e[0] | ((unsigned)e[1] << 16);
    q.y = (unsigned)e[2] | ((unsigned)e[3] << 16);
    q.z = (unsigned)e[4] | ((unsigned)e[5] << 16);
    q.w = (unsigned)e[6] | ((unsigned)e[7] << 16);
    wimg[idx] = q;
  }
}

// ---------------- MFMA GEMM: pre16[n][b][ch] = bf16(x @ W) ----------------
// Wave tile: 32 rows x 64 cols. 4 waves/block. nWaveTiles = M/32.
__global__ __launch_bounds__(256) void gemm_mfma_kernel(
    const float* __restrict__ x, const uint4* __restrict__ wimg,
    unsigned short* __restrict__ pre16, int N, int nWaveTiles) {
  __shared__ uint4 wlds[2048];   // 32 KB: 32 fslots x 64 lanes x 16B
  const int t = threadIdx.x;
  for (int i = t; i < 2048; i += 256) wlds[i] = wimg[i];
  __syncthreads();

  const int wtile = blockIdx.x * 4 + (t >> 6);
  if (wtile >= nWaveTiles) return;
  const int lane = t & 63;
  const int rowg = (lane >> 4) & 3;
  const int rloc = lane & 15;

  f32x4 acc[2][4];
#pragma unroll
  for (int rs = 0; rs < 2; ++rs)
#pragma unroll
    for (int ct = 0; ct < 4; ++ct) acc[rs][ct] = (f32x4){0.f, 0.f, 0.f, 0.f};

  const float* xb = x + (size_t)wtile * 32 * DIN;

#pragma unroll
  for (int ks = 0; ks < 4; ++ks) {
    s16x8 Ah[2], Al[2];
#pragma unroll
    for (int rs = 0; rs < 2; ++rs) {
      const float* xp = xb + (rs * 16 + rloc) * DIN + ks * 32 + 4 * rowg;
      float4 a0 = *(const float4*)xp;          // j = 0..3  (k-half 0)
      float4 a1 = *(const float4*)(xp + 16);   // j = 4..7  (k-half 1)

      unsigned b0 = __builtin_bit_cast(unsigned, a0.x);
      unsigned b1 = __builtin_bit_cast(unsigned, a0.y);
      unsigned b2 = __builtin_bit_cast(unsigned, a0.z);
      unsigned b3 = __builtin_bit_cast(unsigned, a0.w);
      unsigned c0 = __builtin_bit_cast(unsigned, a1.x);
      unsigned c1 = __builtin_bit_cast(unsigned, a1.y);
      unsigned c2 = __builtin_bit_cast(unsigned, a1.z);
      unsigned c3 = __builtin_bit_cast(unsigned, a1.w);

      union { s16x8 v; unsigned u[4]; } H, L;
      H.u[0] = (b0 >> 16) | (b1 & 0xffff0000u);
      H.u[1] = (b2 >> 16) | (b3 & 0xffff0000u);
      H.u[2] = (c0 >> 16) | (c1 & 0xffff0000u);
      H.u[3] = (c2 >> 16) | (c3 & 0xffff0000u);

      float l0 = a0.x - hi16(b0);
      float l1 = a0.y - hi16(b1);
      float l2 = a0.z - hi16(b2);
      float l3 = a0.w - hi16(b3);
      float l4 = a1.x - hi16(c0);
      float l5 = a1.y - hi16(c1);
      float l6 = a1.z - hi16(c2);
      float l7 = a1.w - hi16(c3);
      L.u[0] = (__builtin_bit_cast(unsigned, l0) >> 16) |
               (__builtin_bit_cast(unsigned, l1) & 0xffff0000u);
      L.u[1] = (__builtin_bit_cast(unsigned, l2) >> 16) |
               (__builtin_bit_cast(unsigned, l3) & 0xffff0000u);
      L.u[2] = (__builtin_bit_cast(unsigned, l4) >> 16) |
               (__builtin_bit_cast(unsigned, l5) & 0xffff0000u);
      L.u[3] = (__builtin_bit_cast(unsigned, l6) >> 16) |
               (__builtin_bit_cast(unsigned, l7) & 0xffff0000u);
      Ah[rs] = H.v;
      Al[rs] = L.v;
    }

#pragma unroll
    for (int ct = 0; ct < 4; ++ct) {
      const int fbase = (ct * 4 + ks) * 2;
      s16x8 Bh = *(const s16x8*)&wlds[fbase * 64 + lane];
      s16x8 Bl = *(const s16x8*)&wlds[(fbase + 1) * 64 + lane];
#pragma unroll
      for (int rs = 0; rs < 2; ++rs) {
        acc[rs][ct] = __builtin_amdgcn_mfma_f32_16x16x32_bf16(Ah[rs], Bh, acc[rs][ct], 0, 0, 0);
        acc[rs][ct] = __builtin_amdgcn_mfma_f32_16x16x32_bf16(Ah[rs], Bl, acc[rs][ct], 0, 0, 0);
        acc[rs][ct] = __builtin_amdgcn_mfma_f32_16x16x32_bf16(Al[rs], Bh, acc[rs][ct], 0, 0, 0);
      }
    }
  }

  // epilogue: C/D row = 4*(lane>>4)+reg, col = lane&15 (m89-verified)
#pragma unroll
  for (int rs = 0; rs < 2; ++rs) {
#pragma unroll
    for (int r = 0; r < 4; ++r) {
      int m = wtile * 32 + rs * 16 + 4 * rowg + r;   // GEMM row = b*N + n
      int b = m / N;
      int n = m - b * N;
      size_t o = (size_t)n * 256 + b * 64 + rloc;
#pragma unroll
      for (int ct = 0; ct < 4; ++ct) {
        pre16[o + ct * 16] = f2bf(acc[rs][ct][r]);
      }
    }
  }
}

// ---------------- CSR build ----------------
__global__ __launch_bounds__(256) void hist_kernel(
    const int* __restrict__ rows, int* __restrict__ cnt, int nE) {
  int e = blockIdx.x * blockDim.x + threadIdx.x;
  if (e < nE) atomicAdd(&cnt[rows[e]], 1);
}

__global__ __launch_bounds__(1024) void scan1_kernel(
    const int* __restrict__ cnt, int* __restrict__ offs,
    int* __restrict__ bsum, int n) {
  __shared__ int wsum[16];
  const int t = threadIdx.x, lane = t & 63, wv = t >> 6;
  const int i = blockIdx.x * 1024 + t;
  int v = (i < n) ? cnt[i] : 0;
  int s = v;
#pragma unroll
  for (int d = 1; d < 64; d <<= 1) {
    int u = __shfl_up(s, d, 64);
    if (lane >= d) s += u;
  }
  if (lane == 63) wsum[wv] = s;
  __syncthreads();
  if (t < 16) {
    int a = wsum[t];
#pragma unroll
    for (int d = 1; d < 16; d <<= 1) {
      int u = __shfl_up(a, d, 16);
      if (t >= d) a += u;
    }
    wsum[t] = a;
  }
  __syncthreads();
  int woff = wv ? wsum[wv - 1] : 0;
  if (i < n) offs[i] = woff + s - v;
  if (t == 0) bsum[blockIdx.x] = wsum[15];
}

__global__ __launch_bounds__(64) void scan2_kernel(int* __restrict__ bsum, int nb) {
  const int lane = threadIdx.x;
  int v = (lane < nb) ? bsum[lane] : 0;
  int s = v;
#pragma unroll
  for (int d = 1; d < 64; d <<= 1) {
    int u = __shfl_up(s, d, 64);
    if (lane >= d) s += u;
  }
  if (lane < nb) bsum[lane] = s - v;
}

__global__ __launch_bounds__(256) void scan3_kernel(
    int* __restrict__ offs, const int* __restrict__ bsum,
    int* __restrict__ pos, int n, int total) {
  const int i = blockIdx.x * blockDim.x + threadIdx.x;
  if (i < n) {
    int o = offs[i] + bsum[i >> 10];
    offs[i] = o;
    pos[i] = o;
  }
  if (i == 0) offs[n] = total;
}

__global__ __launch_bounds__(256) void fill_kernel(
    const int* __restrict__ rows, const int* __restrict__ cols,
    const float* __restrict__ vals, int* __restrict__ pos,
    int2* __restrict__ epk, int nE) {
  int e = blockIdx.x * blockDim.x + threadIdx.x;
  if (e >= nE) return;
  int p = atomicAdd(&pos[rows[e]], 1);
  epk[p] = make_int2(cols[e], __builtin_bit_cast(int, vals[e]));
}

// ---------------- gather: one wave per destination row, fused ReLU ---------
__global__ __launch_bounds__(256) void gather_rows_kernel(
    const unsigned short* __restrict__ pre16, const int* __restrict__ offs,
    const int2* __restrict__ epk, float* __restrict__ out, int N, int NS) {
  const int wid  = blockIdx.x * 4 + (threadIdx.x >> 6);
  const int lane = threadIdx.x & 63;
  if (wid >= N) return;

  const int start = offs[wid];
  const int end   = offs[wid + 1];
  const int eh    = lane >> 5;
  const int loff  = ((lane >> 3) & 3) * 64 + (lane & 7) * 8;

  float a0 = 0.f, a1 = 0.f, a2 = 0.f, a3 = 0.f;
  float a4 = 0.f, a5 = 0.f, a6 = 0.f, a7 = 0.f;

  for (int j0 = start; j0 < end; j0 += 64) {
    const int m = min(64, end - j0);
    int   c = 0;
    float v = 0.0f;
    if (lane < m) {
      int2 r = epk[j0 + lane];
      c = r.x;
      v = __builtin_bit_cast(float, r.y);
    }

    auto edge2 = [&](int j) {
      int   cj = __shfl(c, j + eh, 64);
      float vj = __shfl(v, j + eh, 64);
      const uint4 q = *(const uint4*)(pre16 + (size_t)cj * 256 + loff);
      a0 = fmaf(vj, lo16(q.x), a0);
      a1 = fmaf(vj, hi16(q.x), a1);
      a2 = fmaf(vj, lo16(q.y), a2);
      a3 = fmaf(vj, hi16(q.y), a3);
      a4 = fmaf(vj, lo16(q.z), a4);
      a5 = fmaf(vj, hi16(q.z), a5);
      a6 = fmaf(vj, lo16(q.w), a6);
      a7 = fmaf(vj, hi16(q.w), a7);
    };

    int j = 0;
    for (; j + 3 < m; j += 4) { edge2(j); edge2(j + 2); }
    for (; j + 1 < m; j += 2) { edge2(j); }
    if (j < m) {
      int   cj = __shfl(c, j, 64);
      float vj = __shfl(v, j, 64);
      if (eh) vj = 0.0f;
      const uint4 q = *(const uint4*)(pre16 + (size_t)cj * 256 + loff);
      a0 = fmaf(vj, lo16(q.x), a0);
      a1 = fmaf(vj, hi16(q.x), a1);
      a2 = fmaf(vj, lo16(q.y), a2);
      a3 = fmaf(vj, hi16(q.y), a3);
      a4 = fmaf(vj, lo16(q.z), a4);
      a5 = fmaf(vj, hi16(q.z), a5);
      a6 = fmaf(vj, lo16(q.w), a6);
      a7 = fmaf(vj, hi16(q.w), a7);
    }
  }

  a0 += __shfl_xor(a0, 32, 64);
  a1 += __shfl_xor(a1, 32, 64);
  a2 += __shfl_xor(a2, 32, 64);
  a3 += __shfl_xor(a3, 32, 64);
  a4 += __shfl_xor(a4, 32, 64);
  a5 += __shfl_xor(a5, 32, 64);
  a6 += __shfl_xor(a6, 32, 64);
  a7 += __shfl_xor(a7, 32, 64);

  if (lane < 32) {
    const int b   = lane >> 3;
    const int ch8 = (lane & 7) * 8;
    size_t o = (size_t)b * NS + (size_t)wid * DOUT + ch8;
    *(float4*)&out[o]     = make_float4(fmaxf(a0, 0.f), fmaxf(a1, 0.f),
                                        fmaxf(a2, 0.f), fmaxf(a3, 0.f));
    *(float4*)&out[o + 4] = make_float4(fmaxf(a4, 0.f), fmaxf(a5, 0.f),
                                        fmaxf(a6, 0.f), fmaxf(a7, 0.f));
  }
}

extern "C" void kernel_launch(void* const* d_in, const int* in_sizes, int n_in,
                              void* d_out, int out_size, void* d_ws, size_t ws_size,
                              hipStream_t stream) {
  const float* x     = (const float*)d_in[0];
  const float* w     = (const float*)d_in[1];
  const float* evals = (const float*)d_in[2];
  const int*   erows = (const int*)d_in[3];
  const int*   ecols = (const int*)d_in[4];
  float* out = (float*)d_out;

  const int N  = in_sizes[0] / (B_BATCH * DIN);   // 50000
  const int E  = in_sizes[2];                     // 800000
  const int M  = B_BATCH * N;                     // 200000
  const int NS = N * DOUT;
  const int NB = (N + 1023) / 1024;
  const int nWaveTiles = M / 32;                  // 6250 (M % 32 == 0)

  size_t off = 0;
  auto alloc = [&](size_t bytes) {
    size_t o = off;
    off += (bytes + 255) & ~(size_t)255;
    return o;
  };
  size_t pre_off  = alloc((size_t)M * DOUT * 2);   // 25.6 MB
  size_t wimg_off = alloc((size_t)2048 * 16);      // 32 KB
  size_t cnt_off  = alloc((size_t)N * 4);
  size_t offs_off = alloc((size_t)(N + 1) * 4);
  size_t pos_off  = alloc((size_t)(N + 1) * 4);
  size_t epk_off  = alloc((size_t)E * 8);
  size_t bsum_off = alloc((size_t)64 * 4);
  (void)ws_size;

  char* ws = (char*)d_ws;
  unsigned short* pre16 = (unsigned short*)(ws + pre_off);
  uint4* wimg = (uint4*)(ws + wimg_off);
  int*   cnt  = (int*)(ws + cnt_off);
  int*   offs = (int*)(ws + offs_off);
  int*   pos  = (int*)(ws + pos_off);
  int2*  epk  = (int2*)(ws + epk_off);
  int*   bsum = (int*)(ws + bsum_off);

  // 1) W fragment image, then MFMA GEMM
  prep_wfrag_kernel<<<1, 256, 0, stream>>>(w, wimg);
  gemm_mfma_kernel<<<(nWaveTiles + 3) / 4, 256, 0, stream>>>(x, wimg, pre16, N, nWaveTiles);

  // 2) CSR by destination row
  hipMemsetAsync(cnt, 0, (size_t)N * 4, stream);
  hist_kernel<<<(E + 255) / 256, 256, 0, stream>>>(erows, cnt, E);
  scan1_kernel<<<NB, 1024, 0, stream>>>(cnt, offs, bsum, N);
  scan2_kernel<<<1, 64, 0, stream>>>(bsum, NB);
  scan3_kernel<<<(N + 255) / 256, 256, 0, stream>>>(offs, bsum, pos, N, E);
  fill_kernel<<<(E + 255) / 256, 256, 0, stream>>>(erows, ecols, evals, pos, epk, E);

  // 3) gather + fused ReLU
  gather_rows_kernel<<<(N + 3) / 4, 256, 0, stream>>>(pre16, offs, epk, out, N, NS);
}

// Round 5
// 184.235 us; speedup vs baseline: 4.0753x; 1.0375x over previous
//
#include <hip/hip_runtime.h>
#include <hip/hip_bf16.h>

// x [B=4, N=50000, Din=128] fp32, W [128,64] fp32, E=800000 COO edges (shared
// across batch). out = relu( segsum_rows( pre[:,cols,:] * vals ) ), pre = x@W.
//
// R5: custom zero kernel (runtime fillBuffer was 62us for 200KB!), deeper
// gather unroll (8 loads in flight). GEMM/CSR path unchanged from R4.

#define B_BATCH 4
#define DIN 128
#define DOUT 64

typedef float f32x4 __attribute__((ext_vector_type(4)));
typedef short s16x8 __attribute__((ext_vector_type(8)));

static __device__ __forceinline__ unsigned short f2bf(float f) {
  unsigned u = __builtin_bit_cast(unsigned, f);
  unsigned r = (u + 0x7fff + ((u >> 16) & 1)) >> 16;   // RNE
  return (unsigned short)r;
}
static __device__ __forceinline__ float lo16(unsigned u) {
  return __builtin_bit_cast(float, u << 16);
}
static __device__ __forceinline__ float hi16(unsigned u) {
  return __builtin_bit_cast(float, u & 0xffff0000u);
}

// ---------------- prep: build W fragment image (hi/lo bf16) ----------------
__global__ __launch_bounds__(256) void prep_wfrag_kernel(
    const float* __restrict__ w, uint4* __restrict__ wimg) {
  const int t = threadIdx.x;
  for (int i = 0; i < 8; ++i) {
    int idx = i * 256 + t;           // 0..2047
    int fslot = idx >> 6;
    int lane = idx & 63;
    int term = fslot & 1;
    int cks = fslot >> 1;
    int ct = cks >> 2, ks = cks & 3;
    int n = ct * 16 + (lane & 15);
    int kb = ks * 32 + 4 * ((lane >> 4) & 3);
    unsigned short e[8];
#pragma unroll
    for (int j = 0; j < 8; ++j) {
      int k = kb + 16 * (j >> 2) + (j & 3);
      float wv = w[k * DOUT + n];
      unsigned ub = __builtin_bit_cast(unsigned, wv);
      unsigned hib = ub & 0xffff0000u;
      if (term == 0) {
        e[j] = (unsigned short)(hib >> 16);
      } else {
        float lof = wv - __builtin_bit_cast(float, hib);
        e[j] = (unsigned short)(__builtin_bit_cast(unsigned, lof) >> 16);
      }
    }
    uint4 q;
    q.x = (unsigned)e[0] | ((unsigned)e[1] << 16);
    q.y = (unsigned)e[2] | ((unsigned)e[3] << 16);
    q.z = (unsigned)e[4] | ((unsigned)e[5] << 16);
    q.w = (unsigned)e[6] | ((unsigned)e[7] << 16);
    wimg[idx] = q;
  }
}

// ---------------- MFMA GEMM: pre16[n][b][ch] = bf16(x @ W) ----------------
__global__ __launch_bounds__(256) void gemm_mfma_kernel(
    const float* __restrict__ x, const uint4* __restrict__ wimg,
    unsigned short* __restrict__ pre16, int N, int nWaveTiles) {
  __shared__ uint4 wlds[2048];   // 32 KB
  const int t = threadIdx.x;
  for (int i = t; i < 2048; i += 256) wlds[i] = wimg[i];
  __syncthreads();

  const int wtile = blockIdx.x * 4 + (t >> 6);
  if (wtile >= nWaveTiles) return;
  const int lane = t & 63;
  const int rowg = (lane >> 4) & 3;
  const int rloc = lane & 15;

  f32x4 acc[2][4];
#pragma unroll
  for (int rs = 0; rs < 2; ++rs)
#pragma unroll
    for (int ct = 0; ct < 4; ++ct) acc[rs][ct] = (f32x4){0.f, 0.f, 0.f, 0.f};

  const float* xb = x + (size_t)wtile * 32 * DIN;

#pragma unroll
  for (int ks = 0; ks < 4; ++ks) {
    s16x8 Ah[2], Al[2];
#pragma unroll
    for (int rs = 0; rs < 2; ++rs) {
      const float* xp = xb + (rs * 16 + rloc) * DIN + ks * 32 + 4 * rowg;
      float4 a0 = *(const float4*)xp;          // j = 0..3
      float4 a1 = *(const float4*)(xp + 16);   // j = 4..7

      unsigned b0 = __builtin_bit_cast(unsigned, a0.x);
      unsigned b1 = __builtin_bit_cast(unsigned, a0.y);
      unsigned b2 = __builtin_bit_cast(unsigned, a0.z);
      unsigned b3 = __builtin_bit_cast(unsigned, a0.w);
      unsigned c0 = __builtin_bit_cast(unsigned, a1.x);
      unsigned c1 = __builtin_bit_cast(unsigned, a1.y);
      unsigned c2 = __builtin_bit_cast(unsigned, a1.z);
      unsigned c3 = __builtin_bit_cast(unsigned, a1.w);

      union { s16x8 v; unsigned u[4]; } H, L;
      H.u[0] = (b0 >> 16) | (b1 & 0xffff0000u);
      H.u[1] = (b2 >> 16) | (b3 & 0xffff0000u);
      H.u[2] = (c0 >> 16) | (c1 & 0xffff0000u);
      H.u[3] = (c2 >> 16) | (c3 & 0xffff0000u);

      float l0 = a0.x - hi16(b0);
      float l1 = a0.y - hi16(b1);
      float l2 = a0.z - hi16(b2);
      float l3 = a0.w - hi16(b3);
      float l4 = a1.x - hi16(c0);
      float l5 = a1.y - hi16(c1);
      float l6 = a1.z - hi16(c2);
      float l7 = a1.w - hi16(c3);
      L.u[0] = (__builtin_bit_cast(unsigned, l0) >> 16) |
               (__builtin_bit_cast(unsigned, l1) & 0xffff0000u);
      L.u[1] = (__builtin_bit_cast(unsigned, l2) >> 16) |
               (__builtin_bit_cast(unsigned, l3) & 0xffff0000u);
      L.u[2] = (__builtin_bit_cast(unsigned, l4) >> 16) |
               (__builtin_bit_cast(unsigned, l5) & 0xffff0000u);
      L.u[3] = (__builtin_bit_cast(unsigned, l6) >> 16) |
               (__builtin_bit_cast(unsigned, l7) & 0xffff0000u);
      Ah[rs] = H.v;
      Al[rs] = L.v;
    }

#pragma unroll
    for (int ct = 0; ct < 4; ++ct) {
      const int fbase = (ct * 4 + ks) * 2;
      s16x8 Bh = *(const s16x8*)&wlds[fbase * 64 + lane];
      s16x8 Bl = *(const s16x8*)&wlds[(fbase + 1) * 64 + lane];
#pragma unroll
      for (int rs = 0; rs < 2; ++rs) {
        acc[rs][ct] = __builtin_amdgcn_mfma_f32_16x16x32_bf16(Ah[rs], Bh, acc[rs][ct], 0, 0, 0);
        acc[rs][ct] = __builtin_amdgcn_mfma_f32_16x16x32_bf16(Ah[rs], Bl, acc[rs][ct], 0, 0, 0);
        acc[rs][ct] = __builtin_amdgcn_mfma_f32_16x16x32_bf16(Al[rs], Bh, acc[rs][ct], 0, 0, 0);
      }
    }
  }

#pragma unroll
  for (int rs = 0; rs < 2; ++rs) {
#pragma unroll
    for (int r = 0; r < 4; ++r) {
      int m = wtile * 32 + rs * 16 + 4 * rowg + r;
      int b = m / N;
      int n = m - b * N;
      size_t o = (size_t)n * 256 + b * 64 + rloc;
#pragma unroll
      for (int ct = 0; ct < 4; ++ct) {
        pre16[o + ct * 16] = f2bf(acc[rs][ct][r]);
      }
    }
  }
}

// ---------------- CSR build ----------------
__global__ __launch_bounds__(256) void zero_kernel(int* __restrict__ p, int n) {
  int i = blockIdx.x * blockDim.x + threadIdx.x;
  if (i < n) p[i] = 0;
}

__global__ __launch_bounds__(256) void hist_kernel(
    const int* __restrict__ rows, int* __restrict__ cnt, int nE) {
  int e = blockIdx.x * blockDim.x + threadIdx.x;
  if (e < nE) atomicAdd(&cnt[rows[e]], 1);
}

__global__ __launch_bounds__(1024) void scan1_kernel(
    const int* __restrict__ cnt, int* __restrict__ offs,
    int* __restrict__ bsum, int n) {
  __shared__ int wsum[16];
  const int t = threadIdx.x, lane = t & 63, wv = t >> 6;
  const int i = blockIdx.x * 1024 + t;
  int v = (i < n) ? cnt[i] : 0;
  int s = v;
#pragma unroll
  for (int d = 1; d < 64; d <<= 1) {
    int u = __shfl_up(s, d, 64);
    if (lane >= d) s += u;
  }
  if (lane == 63) wsum[wv] = s;
  __syncthreads();
  if (t < 16) {
    int a = wsum[t];
#pragma unroll
    for (int d = 1; d < 16; d <<= 1) {
      int u = __shfl_up(a, d, 16);
      if (t >= d) a += u;
    }
    wsum[t] = a;
  }
  __syncthreads();
  int woff = wv ? wsum[wv - 1] : 0;
  if (i < n) offs[i] = woff + s - v;
  if (t == 0) bsum[blockIdx.x] = wsum[15];
}

__global__ __launch_bounds__(64) void scan2_kernel(int* __restrict__ bsum, int nb) {
  const int lane = threadIdx.x;
  int v = (lane < nb) ? bsum[lane] : 0;
  int s = v;
#pragma unroll
  for (int d = 1; d < 64; d <<= 1) {
    int u = __shfl_up(s, d, 64);
    if (lane >= d) s += u;
  }
  if (lane < nb) bsum[lane] = s - v;
}

__global__ __launch_bounds__(256) void scan3_kernel(
    int* __restrict__ offs, const int* __restrict__ bsum,
    int* __restrict__ pos, int n, int total) {
  const int i = blockIdx.x * blockDim.x + threadIdx.x;
  if (i < n) {
    int o = offs[i] + bsum[i >> 10];
    offs[i] = o;
    pos[i] = o;
  }
  if (i == 0) offs[n] = total;
}

__global__ __launch_bounds__(256) void fill_kernel(
    const int* __restrict__ rows, const int* __restrict__ cols,
    const float* __restrict__ vals, int* __restrict__ pos,
    int2* __restrict__ epk, int nE) {
  int e = blockIdx.x * blockDim.x + threadIdx.x;
  if (e >= nE) return;
  int p = atomicAdd(&pos[rows[e]], 1);
  epk[p] = make_int2(cols[e], __builtin_bit_cast(int, vals[e]));
}

// ---------------- gather: one wave per destination row, fused ReLU ---------
__global__ __launch_bounds__(256) void gather_rows_kernel(
    const unsigned short* __restrict__ pre16, const int* __restrict__ offs,
    const int2* __restrict__ epk, float* __restrict__ out, int N, int NS) {
  const int wid  = blockIdx.x * 4 + (threadIdx.x >> 6);
  const int lane = threadIdx.x & 63;
  if (wid >= N) return;

  const int start = offs[wid];
  const int end   = offs[wid + 1];
  const int eh    = lane >> 5;
  const int loff  = ((lane >> 3) & 3) * 64 + (lane & 7) * 8;

  float a0 = 0.f, a1 = 0.f, a2 = 0.f, a3 = 0.f;
  float a4 = 0.f, a5 = 0.f, a6 = 0.f, a7 = 0.f;

  for (int j0 = start; j0 < end; j0 += 64) {
    const int m = min(64, end - j0);
    int   c = 0;
    float v = 0.0f;
    if (lane < m) {
      int2 r = epk[j0 + lane];
      c = r.x;
      v = __builtin_bit_cast(float, r.y);
    }

    auto edge2 = [&](int j) {
      int   cj = __shfl(c, j + eh, 64);
      float vj = __shfl(v, j + eh, 64);
      const uint4 q = *(const uint4*)(pre16 + (size_t)cj * 256 + loff);
      a0 = fmaf(vj, lo16(q.x), a0);
      a1 = fmaf(vj, hi16(q.x), a1);
      a2 = fmaf(vj, lo16(q.y), a2);
      a3 = fmaf(vj, hi16(q.y), a3);
      a4 = fmaf(vj, lo16(q.z), a4);
      a5 = fmaf(vj, hi16(q.z), a5);
      a6 = fmaf(vj, lo16(q.w), a6);
      a7 = fmaf(vj, hi16(q.w), a7);
    };

    int j = 0;
    for (; j + 7 < m; j += 8) { edge2(j); edge2(j + 2); edge2(j + 4); edge2(j + 6); }
    for (; j + 1 < m; j += 2) { edge2(j); }
    if (j < m) {   // odd tail
      int   cj = __shfl(c, j, 64);
      float vj = __shfl(v, j, 64);
      if (eh) vj = 0.0f;
      const uint4 q = *(const uint4*)(pre16 + (size_t)cj * 256 + loff);
      a0 = fmaf(vj, lo16(q.x), a0);
      a1 = fmaf(vj, hi16(q.x), a1);
      a2 = fmaf(vj, lo16(q.y), a2);
      a3 = fmaf(vj, hi16(q.y), a3);
      a4 = fmaf(vj, lo16(q.z), a4);
      a5 = fmaf(vj, hi16(q.z), a5);
      a6 = fmaf(vj, lo16(q.w), a6);
      a7 = fmaf(vj, hi16(q.w), a7);
    }
  }

  a0 += __shfl_xor(a0, 32, 64);
  a1 += __shfl_xor(a1, 32, 64);
  a2 += __shfl_xor(a2, 32, 64);
  a3 += __shfl_xor(a3, 32, 64);
  a4 += __shfl_xor(a4, 32, 64);
  a5 += __shfl_xor(a5, 32, 64);
  a6 += __shfl_xor(a6, 32, 64);
  a7 += __shfl_xor(a7, 32, 64);

  if (lane < 32) {
    const int b   = lane >> 3;
    const int ch8 = (lane & 7) * 8;
    size_t o = (size_t)b * NS + (size_t)wid * DOUT + ch8;
    *(float4*)&out[o]     = make_float4(fmaxf(a0, 0.f), fmaxf(a1, 0.f),
                                        fmaxf(a2, 0.f), fmaxf(a3, 0.f));
    *(float4*)&out[o + 4] = make_float4(fmaxf(a4, 0.f), fmaxf(a5, 0.f),
                                        fmaxf(a6, 0.f), fmaxf(a7, 0.f));
  }
}

extern "C" void kernel_launch(void* const* d_in, const int* in_sizes, int n_in,
                              void* d_out, int out_size, void* d_ws, size_t ws_size,
                              hipStream_t stream) {
  const float* x     = (const float*)d_in[0];
  const float* w     = (const float*)d_in[1];
  const float* evals = (const float*)d_in[2];
  const int*   erows = (const int*)d_in[3];
  const int*   ecols = (const int*)d_in[4];
  float* out = (float*)d_out;

  const int N  = in_sizes[0] / (B_BATCH * DIN);   // 50000
  const int E  = in_sizes[2];                     // 800000
  const int M  = B_BATCH * N;                     // 200000
  const int NS = N * DOUT;
  const int NB = (N + 1023) / 1024;
  const int nWaveTiles = M / 32;

  size_t off = 0;
  auto alloc = [&](size_t bytes) {
    size_t o = off;
    off += (bytes + 255) & ~(size_t)255;
    return o;
  };
  size_t pre_off  = alloc((size_t)M * DOUT * 2);   // 25.6 MB
  size_t wimg_off = alloc((size_t)2048 * 16);      // 32 KB
  size_t cnt_off  = alloc((size_t)N * 4);
  size_t offs_off = alloc((size_t)(N + 1) * 4);
  size_t pos_off  = alloc((size_t)(N + 1) * 4);
  size_t epk_off  = alloc((size_t)E * 8);
  size_t bsum_off = alloc((size_t)64 * 4);
  (void)ws_size;

  char* ws = (char*)d_ws;
  unsigned short* pre16 = (unsigned short*)(ws + pre_off);
  uint4* wimg = (uint4*)(ws + wimg_off);
  int*   cnt  = (int*)(ws + cnt_off);
  int*   offs = (int*)(ws + offs_off);
  int*   pos  = (int*)(ws + pos_off);
  int2*  epk  = (int2*)(ws + epk_off);
  int*   bsum = (int*)(ws + bsum_off);

  // 1) W fragment image, then MFMA GEMM
  prep_wfrag_kernel<<<1, 256, 0, stream>>>(w, wimg);
  gemm_mfma_kernel<<<(nWaveTiles + 3) / 4, 256, 0, stream>>>(x, wimg, pre16, N, nWaveTiles);

  // 2) CSR by destination row
  zero_kernel<<<(N + 255) / 256, 256, 0, stream>>>(cnt, N);
  hist_kernel<<<(E + 255) / 256, 256, 0, stream>>>(erows, cnt, E);
  scan1_kernel<<<NB, 1024, 0, stream>>>(cnt, offs, bsum, N);
  scan2_kernel<<<1, 64, 0, stream>>>(bsum, NB);
  scan3_kernel<<<(N + 255) / 256, 256, 0, stream>>>(offs, bsum, pos, N, E);
  fill_kernel<<<(E + 255) / 256, 256, 0, stream>>>(erows, ecols, evals, pos, epk, E);

  // 3) gather + fused ReLU
  gather_rows_kernel<<<(N + 3) / 4, 256, 0, stream>>>(pre16, offs, epk, out, N, NS);
}